// Round 1
// baseline (60.640 us; speedup 1.0000x reference)
//
#include <hip/hip_runtime.h>

typedef __attribute__((ext_vector_type(8))) short short8;
typedef __attribute__((ext_vector_type(4))) float f32x4;

#define B_TOTAL 20000
#define B_PAD   20096   // 157 * 128
#define NF      256
#define K2      512
#define NS      10

__device__ __forceinline__ unsigned short f2bf(float x) {
    unsigned u = __builtin_bit_cast(unsigned, x);
    u += 0x7FFFu + ((u >> 16) & 1u);   // round-to-nearest-even
    return (unsigned short)(u >> 16);
}

// Kernel A: build combined [B_PAD][512] bf16 rows in ws; blocks 0..127 also convert weight f32->bf16.
__global__ __launch_bounds__(256) void gather_combine(
    const float* __restrict__ ue, const int* __restrict__ nidx,
    const int* __restrict__ nodes, const float* __restrict__ w,
    unsigned short* __restrict__ comb, unsigned short* __restrict__ wbf)
{
    const int t = threadIdx.x, blk = blockIdx.x;
    if (blk < 128) {                       // 128 blocks * 256 thr * 4 = 131072 = 256*512 weight elems
        const int base = blk * 1024 + t * 4;
        const float4 v = *(const float4*)(w + base);
        ushort4 o;
        o.x = f2bf(v.x); o.y = f2bf(v.y); o.z = f2bf(v.z); o.w = f2bf(v.w);
        *(ushort4*)(wbf + base) = o;
    }
    const int lane = t & 63;
    const int b = blk * 4 + (t >> 6);      // one wave per b-row
    if (b >= B_PAD) return;
    unsigned short* crow = comb + (size_t)b * K2;
    if (b < B_TOTAL) {
        const int node = nodes[b];
        const float4 sf = ((const float4*)(ue + (size_t)node * NF))[lane];
        int myidx = 0;
        if (lane < NS) myidx = nidx[b * NS + lane];
        float ax = 0.f, ay = 0.f, az = 0.f, aw = 0.f;
        #pragma unroll
        for (int s = 0; s < NS; ++s) {
            const int is = __shfl(myidx, s);
            const float4 v = ((const float4*)(ue + (size_t)is * NF))[lane];
            ax += v.x; ay += v.y; az += v.z; aw += v.w;
        }
        const float inv = 1.0f / 11.0f;    // reference divides by S+1
        ushort4 s4, n4;
        s4.x = f2bf(sf.x); s4.y = f2bf(sf.y); s4.z = f2bf(sf.z); s4.w = f2bf(sf.w);
        n4.x = f2bf(ax * inv); n4.y = f2bf(ay * inv); n4.z = f2bf(az * inv); n4.w = f2bf(aw * inv);
        *(ushort4*)(crow + lane * 4) = s4;
        *(ushort4*)(crow + NF + lane * 4) = n4;
    } else {                               // zero the pad rows (ws is poisoned, not zeroed)
        ushort4 z; z.x = z.y = z.z = z.w = 0;
        *(ushort4*)(crow + lane * 4) = z;
        *(ushort4*)(crow + NF + lane * 4) = z;
    }
}

// Kernel B: out[e][b] = relu(sum_k W[e][k] * comb[b][k]), MFMA bf16, 128x128 tile, BK=32.
// LDS layout per tile: [kgroup 4][row 128][8 bf16] -> ds_read_b128 conflict-free.
__global__ __launch_bounds__(256) void gemm_relu(
    const unsigned short* __restrict__ wbf,   // [256][512] bf16
    const unsigned short* __restrict__ comb,  // [B_PAD][512] bf16
    float* __restrict__ out)                  // [256][20000] f32
{
    __shared__ unsigned short Alds[4096];  // 8 KB
    __shared__ unsigned short Blds[4096];  // 8 KB
    const int t    = threadIdx.x;
    const int lane = t & 63;
    const int wv   = t >> 6;
    const int wm   = wv >> 1, wn = wv & 1;     // 2x2 wave grid, 64x64 per wave
    const int n0   = blockIdx.x * 128;         // b-tile
    const int m0   = blockIdx.y * 128;         // e-tile
    const int srow = t & 127;                  // staging row
    const int skg  = t >> 7;                   // staging k-group (0/1; +2 for 2nd load)
    const int fr   = lane & 15;
    const int kq   = lane >> 4;

    f32x4 acc[4][4] = {};

    const short8* A8 = (const short8*)Alds;
    const short8* B8 = (const short8*)Blds;

    for (int ks = 0; ks < 16; ++ks) {
        const unsigned short* ga = wbf  + (size_t)(m0 + srow) * K2 + ks * 32 + skg * 8;
        const unsigned short* gb = comb + (size_t)(n0 + srow) * K2 + ks * 32 + skg * 8;
        unsigned short* la = Alds + t * 8;     // dest linear in t -> wave-uniform base + lane*16
        unsigned short* lb = Blds + t * 8;
        __builtin_amdgcn_global_load_lds((const __attribute__((address_space(1))) void*)ga,
            (__attribute__((address_space(3))) void*)la, 16, 0, 0);
        __builtin_amdgcn_global_load_lds((const __attribute__((address_space(1))) void*)(ga + 16),
            (__attribute__((address_space(3))) void*)(la + 2048), 16, 0, 0);
        __builtin_amdgcn_global_load_lds((const __attribute__((address_space(1))) void*)gb,
            (__attribute__((address_space(3))) void*)lb, 16, 0, 0);
        __builtin_amdgcn_global_load_lds((const __attribute__((address_space(1))) void*)(gb + 16),
            (__attribute__((address_space(3))) void*)(lb + 2048), 16, 0, 0);
        asm volatile("s_waitcnt vmcnt(0)" ::: "memory");
        __syncthreads();

        short8 af[4], bg[4];
        #pragma unroll
        for (int i = 0; i < 4; ++i)
            af[i] = A8[kq * 128 + wm * 64 + i * 16 + fr];
        #pragma unroll
        for (int j = 0; j < 4; ++j)
            bg[j] = B8[kq * 128 + wn * 64 + j * 16 + fr];
        #pragma unroll
        for (int i = 0; i < 4; ++i)
            #pragma unroll
            for (int j = 0; j < 4; ++j)
                acc[i][j] = __builtin_amdgcn_mfma_f32_16x16x32_bf16(af[i], bg[j], acc[i][j], 0, 0, 0);
        __syncthreads();
    }

    #pragma unroll
    for (int i = 0; i < 4; ++i) {
        const int e = m0 + wm * 64 + i * 16 + kq * 4;
        #pragma unroll
        for (int j = 0; j < 4; ++j) {
            const int b = n0 + wn * 64 + j * 16 + fr;
            if (b < B_TOTAL) {
                #pragma unroll
                for (int r = 0; r < 4; ++r)
                    out[(size_t)(e + r) * B_TOTAL + b] = fmaxf(acc[i][j][r], 0.0f);
            }
        }
    }
}

extern "C" void kernel_launch(void* const* d_in, const int* in_sizes, int n_in,
                              void* d_out, int out_size, void* d_ws, size_t ws_size,
                              hipStream_t stream) {
    const float* ue    = (const float*)d_in[0];
    // d_in[1] = features_ap: unused in ue2ue mode
    const int*   nidx  = (const int*)d_in[2];
    const int*   nodes = (const int*)d_in[3];
    const float* w     = (const float*)d_in[4];
    float*       out   = (float*)d_out;

    unsigned short* comb = (unsigned short*)d_ws;                 // [B_PAD][512] bf16 = 20.58 MB
    unsigned short* wbf  = comb + (size_t)B_PAD * K2;             // [256][512] bf16  = 0.26 MB

    hipLaunchKernelGGL(gather_combine, dim3(B_PAD / 4), dim3(256), 0, stream,
                       ue, nidx, nodes, w, comb, wbf);
    hipLaunchKernelGGL(gemm_relu, dim3(B_PAD / 128, 2), dim3(256), 0, stream,
                       wbf, comb, out);
}